// Round 4
// baseline (321.410 us; speedup 1.0000x reference)
//
#include <hip/hip_runtime.h>

#define NBINS 4
#define BLOCK 256
#define WAVES_PER_BLOCK (BLOCK / 64)
#define NBLOCKS 2048
// Per block-step: 4 waves x 256 pts = 1024 points. Per wave slice: 5 KB
// (x 2KB + y 2KB + d 1KB). Double-buffered: 2*4*5120 = 40960 B -> 4 blocks/CU.
#define SLICE_BYTES 5120
#define BUF_BYTES (WAVES_PER_BLOCK * SLICE_BYTES)
#define PTS_PER_STEP (NBLOCKS * BLOCK * 4)

typedef float f32x4 __attribute__((ext_vector_type(4)));

struct WS {
    float sum_v[NBINS];  // per-bin sum of 0.5*d2 + 0.1*ad2
    float cnt[NBINS];    // per-bin count (exact in float up to 2^24)
};

// Per-point update, branchless. One raw v_sqrt per point:
// (|x|-|y|)^2 = sx + sy - 2*sqrt(sx*sy). Exclusive binning (ref double-counts
// exact boundary points; ~1 point in 16.7M, error ~2e-7 << 0.166 threshold).
__device__ __forceinline__ void accum_point(float x0, float x1, float y0, float y1,
                                            float d,
                                            float (&acc)[NBINS], float (&cnt)[NBINS]) {
    float sx = fmaf(x1, x1, x0 * x0);
    float sy = fmaf(y1, y1, y0 * y0);
    float dx0 = x0 - y0, dx1 = x1 - y1;
    float d2 = fmaf(dx1, dx1, dx0 * dx0);
    float t = __builtin_amdgcn_sqrtf(sx * sy);  // raw v_sqrt_f32, ~1 ulp
    float ad2 = sx + sy - 2.0f * t;             // (|x|-|y|)^2
    float v = fmaf(0.1f, ad2, 0.5f * d2);
    bool c1 = d < 0.25f;
    bool c2 = d < 0.5f;
    bool c3 = d < 0.75f;
    float m0 = c1 ? 1.0f : 0.0f;
    float m1 = (c2 && !c1) ? 1.0f : 0.0f;
    float m2 = (c3 && !c2) ? 1.0f : 0.0f;
    float m3 = c3 ? 0.0f : 1.0f;
    acc[0] = fmaf(v, m0, acc[0]);
    acc[1] = fmaf(v, m1, acc[1]);
    acc[2] = fmaf(v, m2, acc[2]);
    acc[3] = fmaf(v, m3, acc[3]);
    cnt[0] += m0;
    cnt[1] += m1;
    cnt[2] += m2;
    cnt[3] += m3;
}

// global -> LDS direct DMA (bypasses the TCP->VGPR miss-return path, which the
// R0-R3 counter trail indicts as a ~1 line/10cyc/CU throughput cap: delivered
// BW pinned at 3.94 TB/s = 256 CU * 64B / 10cyc regardless of access order
// (R1), per-wave MLP depth (R2), or nt hints (R3: +44% but new flat ceiling)).
// Dest is wave-uniform base; HW writes lane l at base + l*16.
#define GLDS(gaddr, laddr)                                                        \
    __builtin_amdgcn_global_load_lds(                                             \
        (const __attribute__((address_space(1))) void*)(gaddr),                   \
        (__attribute__((address_space(3))) void*)(laddr), 16, 0, 0)

__global__ __launch_bounds__(BLOCK, 4) void radial_loss_main(
    const float* __restrict__ x, const float* __restrict__ y,
    const float* __restrict__ dist, WS* __restrict__ ws, int n) {
    // Staging buffer; reused (post-barrier) for the final cross-wave reduction.
    __shared__ __align__(16) char smem[2 * BUF_BYTES];

    float acc[NBINS] = {0.f, 0.f, 0.f, 0.f};
    float cnt[NBINS] = {0.f, 0.f, 0.f, 0.f};

    const int w = threadIdx.x >> 6;
    const int l = threadIdx.x & 63;
    const int nsteps = n / PTS_PER_STEP;  // 8 full steps at N=16.7M (exact)

    char* slice0 = smem + w * SLICE_BYTES;
    char* slice1 = smem + BUF_BYTES + w * SLICE_BYTES;

    // Stage one wave-step: 256 consecutive points for this wave.
    // Layout in slice (lane-linear, = straight copy of global):
    //   [0,2048)   x for pts [0,256)   (pt j at byte 8j)
    //   [2048,4096) y likewise
    //   [4096,5120) d for pts (pt j at byte 4j)
    auto issue = [&](int t, char* slice) {
        const int ptb = (t * NBLOCKS + blockIdx.x) * (BLOCK * 4) + w * 256;
        const char* xs = (const char*)x + (size_t)ptb * 8;
        const char* ys = (const char*)y + (size_t)ptb * 8;
        const char* ds = (const char*)dist + (size_t)ptb * 4;
        GLDS(xs + l * 16, slice);
        GLDS(xs + 1024 + l * 16, slice + 1024);
        GLDS(ys + l * 16, slice + 2048);
        GLDS(ys + 1024 + l * 16, slice + 3072);
        GLDS(ds + l * 16, slice + 4096);
    };

    // Consume this wave's private slice: lane l owns pts 4l..4l+3.
    auto consume = [&](const char* slice) {
        f32x4 xv0 = *(const f32x4*)(slice + 32 * l);
        f32x4 xv1 = *(const f32x4*)(slice + 32 * l + 16);
        f32x4 yv0 = *(const f32x4*)(slice + 2048 + 32 * l);
        f32x4 yv1 = *(const f32x4*)(slice + 2048 + 32 * l + 16);
        f32x4 dv = *(const f32x4*)(slice + 4096 + 16 * l);
        accum_point(xv0.x, xv0.y, yv0.x, yv0.y, dv.x, acc, cnt);
        accum_point(xv0.z, xv0.w, yv0.z, yv0.w, dv.y, acc, cnt);
        accum_point(xv1.x, xv1.y, yv1.x, yv1.y, dv.z, acc, cnt);
        accum_point(xv1.z, xv1.w, yv1.z, yv1.w, dv.w, acc, cnt);
    };

    // Wave-private double-buffered pipeline: no __syncthreads in the loop.
    // Counted vmcnt(5): while consuming step t, step t+1's 5 DMAs stay in flight.
    if (nsteps >= 1) {
        issue(0, slice0);
        char* cur = slice0;
        char* nxt = slice1;
        for (int t = 0; t + 1 < nsteps; ++t) {
            issue(t + 1, nxt);
            asm volatile("s_waitcnt vmcnt(5)" ::: "memory");
            __builtin_amdgcn_sched_barrier(0);
            consume(cur);
            char* tmp = cur; cur = nxt; nxt = tmp;
        }
        asm volatile("s_waitcnt vmcnt(0)" ::: "memory");
        __builtin_amdgcn_sched_barrier(0);
        consume(cur);
    }

    // Remainder points [nsteps*PTS_PER_STEP, n): plain per-thread path
    // (empty at N=16.7M where n == 8 * PTS_PER_STEP exactly).
    for (int p = nsteps * PTS_PER_STEP + blockIdx.x * BLOCK + threadIdx.x; p < n;
         p += NBLOCKS * BLOCK) {
        accum_point(x[2 * p], x[2 * p + 1], y[2 * p], y[2 * p + 1], dist[p], acc,
                    cnt);
    }

    // wave-64 shuffle reduction (8 values)
#pragma unroll
    for (int off = 32; off > 0; off >>= 1) {
#pragma unroll
        for (int b = 0; b < NBINS; ++b) {
            acc[b] += __shfl_down(acc[b], off);
            cnt[b] += __shfl_down(cnt[b], off);
        }
    }

    // Cross-wave reduction, reusing the staging LDS (barrier first: waves are
    // NOT synchronized in the main loop and slices alias this region).
    __syncthreads();
    float* sm_v = (float*)smem;                       // [WAVES][NBINS]
    float* sm_c = sm_v + WAVES_PER_BLOCK * NBINS;     // [WAVES][NBINS]
    if (l == 0) {
#pragma unroll
        for (int b = 0; b < NBINS; ++b) {
            sm_v[w * NBINS + b] = acc[b];
            sm_c[w * NBINS + b] = cnt[b];
        }
    }
    __syncthreads();
    if (threadIdx.x < NBINS) {
        const int b = threadIdx.x;
        float tv = 0.f, tc = 0.f;
#pragma unroll
        for (int wv = 0; wv < WAVES_PER_BLOCK; ++wv) {
            tv += sm_v[wv * NBINS + b];
            tc += sm_c[wv * NBINS + b];
        }
        atomicAdd(&ws->sum_v[b], tv);
        atomicAdd(&ws->cnt[b], tc);
    }
}

__global__ void radial_loss_final(const WS* __restrict__ ws, float* __restrict__ out) {
    if (threadIdx.x == 0 && blockIdx.x == 0) {
        float loss = 0.f;
#pragma unroll
        for (int b = 0; b < NBINS; ++b) {
            float c = ws->cnt[b];
            if (c > 0.f) loss += ws->sum_v[b] / c;
        }
        out[0] = loss;
    }
}

extern "C" void kernel_launch(void* const* d_in, const int* in_sizes, int n_in,
                              void* d_out, int out_size, void* d_ws, size_t ws_size,
                              hipStream_t stream) {
    const float* x = (const float*)d_in[0];
    const float* y = (const float*)d_in[1];
    const float* dist = (const float*)d_in[2];
    float* out = (float*)d_out;
    WS* ws = (WS*)d_ws;
    const int n = in_sizes[2];  // dist element count = N

    hipMemsetAsync(ws, 0, sizeof(WS), stream);
    radial_loss_main<<<NBLOCKS, BLOCK, 0, stream>>>(x, y, dist, ws, n);
    radial_loss_final<<<1, 64, 0, stream>>>(ws, out);
}

// Round 5
// 314.504 us; speedup vs baseline: 1.0220x; 1.0220x over previous
//
#include <hip/hip_runtime.h>

#define NBINS 4
#define BLOCK 256
#define WAVES_PER_BLOCK (BLOCK / 64)
#define NBLOCKS 2048

typedef float f32x4 __attribute__((ext_vector_type(4)));
typedef float f32x2 __attribute__((ext_vector_type(2)));

struct WS {
    float sum_v[NBINS];  // per-bin sum of 0.5*d2 + 0.1*ad2
    float cnt[NBINS];    // per-bin count (exact in float up to 2^24)
};

// Per-point update, branchless. One raw v_sqrt per point:
// (|x|-|y|)^2 = sx + sy - 2*sqrt(sx*sy). Exclusive binning (ref double-counts
// exact boundary points; ~1 point in 16.7M, error ~2e-7 << 0.166 threshold).
__device__ __forceinline__ void accum_point(float x0, float x1, float y0, float y1,
                                            float d,
                                            float (&acc)[NBINS], float (&cnt)[NBINS]) {
    float sx = fmaf(x1, x1, x0 * x0);
    float sy = fmaf(y1, y1, y0 * y0);
    float dx0 = x0 - y0, dx1 = x1 - y1;
    float d2 = fmaf(dx1, dx1, dx0 * dx0);
    float t = __builtin_amdgcn_sqrtf(sx * sy);  // raw v_sqrt_f32, ~1 ulp
    float ad2 = sx + sy - 2.0f * t;             // (|x|-|y|)^2
    float v = fmaf(0.1f, ad2, 0.5f * d2);
    bool c1 = d < 0.25f;
    bool c2 = d < 0.5f;
    bool c3 = d < 0.75f;
    float m0 = c1 ? 1.0f : 0.0f;
    float m1 = (c2 && !c1) ? 1.0f : 0.0f;
    float m2 = (c3 && !c2) ? 1.0f : 0.0f;
    float m3 = c3 ? 0.0f : 1.0f;
    acc[0] = fmaf(v, m0, acc[0]);
    acc[1] = fmaf(v, m1, acc[1]);
    acc[2] = fmaf(v, m2, acc[2]);
    acc[3] = fmaf(v, m3, acc[3]);
    cnt[0] += m0;
    cnt[1] += m1;
    cnt[2] += m2;
    cnt[3] += m3;
}

__device__ __forceinline__ void accum2v(const f32x4 xv, const f32x4 yv,
                                        const f32x2 dv,
                                        float (&acc)[NBINS], float (&cnt)[NBINS]) {
    accum_point(xv.x, xv.y, yv.x, yv.y, dv.x, acc, cnt);
    accum_point(xv.z, xv.w, yv.z, yv.w, dv.y, acc, cnt);
}

// nt loads (R3: +44%, the only positive lever so far) + ISA-enforced depth-4
// ring (R2 structure — untested in the nt regime, where the throughput/latency
// balance changed; compiler collapses source-level pipelines to VGPR=36).
// SGPR base + 32-bit voffset; counted vmcnt keeps 9 loads (3 stages) in flight.
#define GLOAD4NT(dst, base, off) \
    asm volatile("global_load_dwordx4 %0, %1, %2 nt" : "=v"(dst) : "v"(off), "s"(base))
#define GLOAD2NT(dst, base, off) \
    asm volatile("global_load_dwordx2 %0, %1, %2 nt" : "=v"(dst) : "v"(off), "s"(base))
// Counted wait + rule-#18 fence (sched_barrier stops hipcc hoisting dependent
// VALU above the wait; "memory" alone does not order register-only ops).
#define VWAIT(n)                                              \
    do {                                                      \
        asm volatile("s_waitcnt vmcnt(" #n ")" ::: "memory"); \
        __builtin_amdgcn_sched_barrier(0);                    \
    } while (0)

__device__ __forceinline__ f32x4 ntload4(const f32x4* p) {
    return __builtin_nontemporal_load(p);
}
__device__ __forceinline__ f32x2 ntload2(const f32x2* p) {
    return __builtin_nontemporal_load(p);
}

__global__ __launch_bounds__(BLOCK, 4) void radial_loss_main(
    const float* __restrict__ x, const float* __restrict__ y,
    const float* __restrict__ dist, WS* __restrict__ ws, int n) {
    float acc[NBINS] = {0.f, 0.f, 0.f, 0.f};
    float cnt[NBINS] = {0.f, 0.f, 0.f, 0.f};

    const int n2 = n >> 1;  // float4(x,y) / float2(dist) index space: 2 points each
    const int stride = NBLOCKS * BLOCK;  // 524288; n2 = 16*stride at N=16.7M
    const int nfull = n2 / stride;       // uniform full steps for ALL threads
    int i = blockIdx.x * BLOCK + threadIdx.x;

    if (nfull >= 8 && (nfull & 3) == 0) {
        // ---- asm-pipelined nt path (taken for the bench shape: nfull == 16) ----
        f32x4 x0, y0, x1, y1, x2, y2, x3, y3;
        f32x2 d0, d1, d2, d3;
#define ISSUE(j, idx)                                       \
    do {                                                    \
        unsigned o16 = (unsigned)(idx) * 16u;               \
        unsigned o8 = (unsigned)(idx) * 8u;                 \
        GLOAD4NT(x##j, x, o16);                             \
        GLOAD4NT(y##j, y, o16);                             \
        GLOAD2NT(d##j, dist, o8);                           \
    } while (0)
        ISSUE(0, i);
        ISSUE(1, i + stride);
        ISSUE(2, i + 2 * stride);
        ISSUE(3, i + 3 * stride);
        int k = 0;
        for (; k + 8 <= nfull; k += 4) {
            VWAIT(9); accum2v(x0, y0, d0, acc, cnt); ISSUE(0, i + 4 * stride);
            VWAIT(9); accum2v(x1, y1, d1, acc, cnt); ISSUE(1, i + 5 * stride);
            VWAIT(9); accum2v(x2, y2, d2, acc, cnt); ISSUE(2, i + 6 * stride);
            VWAIT(9); accum2v(x3, y3, d3, acc, cnt); ISSUE(3, i + 7 * stride);
            i += 4 * stride;
        }
        // drain: exactly 4 stages (12 loads) outstanding here
        VWAIT(9); accum2v(x0, y0, d0, acc, cnt);
        VWAIT(6); accum2v(x1, y1, d1, acc, cnt);
        VWAIT(3); accum2v(x2, y2, d2, acc, cnt);
        VWAIT(0); accum2v(x3, y3, d3, acc, cnt);
        i += 4 * stride;
#undef ISSUE
    } else {
        // ---- generic fallback (not taken at N=16.7M) ----
        const f32x4* x4 = (const f32x4*)x;
        const f32x4* y4 = (const f32x4*)y;
        const f32x2* dd = (const f32x2*)dist;
        f32x4 xa, ya, xb, yb;
        f32x2 da, db;
        if (nfull >= 1) { xa = ntload4(x4 + i); ya = ntload4(y4 + i); da = ntload2(dd + i); }
        if (nfull >= 2) {
            xb = ntload4(x4 + i + stride);
            yb = ntload4(y4 + i + stride);
            db = ntload2(dd + i + stride);
        }
        for (int k = 0; k + 2 < nfull; ++k) {
            f32x4 xc = ntload4(x4 + i + 2 * stride);
            f32x4 yc = ntload4(y4 + i + 2 * stride);
            f32x2 dc = ntload2(dd + i + 2 * stride);
            accum2v(xa, ya, da, acc, cnt);
            xa = xb; ya = yb; da = db;
            xb = xc; yb = yc; db = dc;
            i += stride;
        }
        if (nfull >= 2) {
            accum2v(xa, ya, da, acc, cnt);
            xa = xb; ya = yb; da = db;
            i += stride;
        }
        if (nfull >= 1) {
            accum2v(xa, ya, da, acc, cnt);
            i += stride;
        }
    }

    // remainder region [nfull*stride, n2): each thread owns at most one index
    if (i < n2) {
        const f32x4* x4 = (const f32x4*)x;
        const f32x4* y4 = (const f32x4*)y;
        const f32x2* dd = (const f32x2*)dist;
        accum2v(ntload4(x4 + i), ntload4(y4 + i), ntload2(dd + i), acc, cnt);
    }
    // odd-n tail (n even in practice)
    if (blockIdx.x == 0) {
        for (int p = (n2 << 1) + threadIdx.x; p < n; p += BLOCK) {
            accum_point(x[2 * p], x[2 * p + 1], y[2 * p], y[2 * p + 1], dist[p],
                        acc, cnt);
        }
    }

    // wave-64 shuffle reduction (8 values)
#pragma unroll
    for (int off = 32; off > 0; off >>= 1) {
#pragma unroll
        for (int b = 0; b < NBINS; ++b) {
            acc[b] += __shfl_down(acc[b], off);
            cnt[b] += __shfl_down(cnt[b], off);
        }
    }

    __shared__ float sm_v[WAVES_PER_BLOCK][NBINS];
    __shared__ float sm_c[WAVES_PER_BLOCK][NBINS];
    const int wave = threadIdx.x >> 6;
    const int lane = threadIdx.x & 63;
    if (lane == 0) {
#pragma unroll
        for (int b = 0; b < NBINS; ++b) {
            sm_v[wave][b] = acc[b];
            sm_c[wave][b] = cnt[b];
        }
    }
    __syncthreads();
    if (threadIdx.x < NBINS) {
        const int b = threadIdx.x;
        float tv = 0.f, tc = 0.f;
#pragma unroll
        for (int w = 0; w < WAVES_PER_BLOCK; ++w) {
            tv += sm_v[w][b];
            tc += sm_c[w][b];
        }
        atomicAdd(&ws->sum_v[b], tv);
        atomicAdd(&ws->cnt[b], tc);
    }
}

__global__ void radial_loss_final(const WS* __restrict__ ws, float* __restrict__ out) {
    if (threadIdx.x == 0 && blockIdx.x == 0) {
        float loss = 0.f;
#pragma unroll
        for (int b = 0; b < NBINS; ++b) {
            float c = ws->cnt[b];
            if (c > 0.f) loss += ws->sum_v[b] / c;
        }
        out[0] = loss;
    }
}

extern "C" void kernel_launch(void* const* d_in, const int* in_sizes, int n_in,
                              void* d_out, int out_size, void* d_ws, size_t ws_size,
                              hipStream_t stream) {
    const float* x = (const float*)d_in[0];
    const float* y = (const float*)d_in[1];
    const float* dist = (const float*)d_in[2];
    float* out = (float*)d_out;
    WS* ws = (WS*)d_ws;
    const int n = in_sizes[2];  // dist element count = N

    hipMemsetAsync(ws, 0, sizeof(WS), stream);
    radial_loss_main<<<NBLOCKS, BLOCK, 0, stream>>>(x, y, dist, ws, n);
    radial_loss_final<<<1, 64, 0, stream>>>(ws, out);
}

// Round 6
// 310.083 us; speedup vs baseline: 1.0365x; 1.0143x over previous
//
#include <hip/hip_runtime.h>

#define NBINS 4
#define BLOCK 256
#define WAVES_PER_BLOCK (BLOCK / 64)
#define NBLOCKS 2048

typedef float f32x4 __attribute__((ext_vector_type(4)));
typedef float f32x2 __attribute__((ext_vector_type(2)));

struct WS {
    float sum_v[NBINS];  // per-bin sum of 0.5*d2 + 0.1*ad2
    float cnt[NBINS];    // per-bin count (exact in float up to 2^24)
};

// Per-point update, branchless. One raw v_sqrt per point:
// (|x|-|y|)^2 = sx + sy - 2*sqrt(sx*sy). Exclusive binning (ref double-counts
// exact boundary points; ~1 point in 16.7M, error ~2e-7 << 0.166 threshold).
__device__ __forceinline__ void accum_point(float x0, float x1, float y0, float y1,
                                            float d,
                                            float (&acc)[NBINS], float (&cnt)[NBINS]) {
    float sx = fmaf(x1, x1, x0 * x0);
    float sy = fmaf(y1, y1, y0 * y0);
    float dx0 = x0 - y0, dx1 = x1 - y1;
    float d2 = fmaf(dx1, dx1, dx0 * dx0);
    float t = __builtin_amdgcn_sqrtf(sx * sy);  // raw v_sqrt_f32, ~1 ulp
    float ad2 = sx + sy - 2.0f * t;             // (|x|-|y|)^2
    float v = fmaf(0.1f, ad2, 0.5f * d2);
    bool c1 = d < 0.25f;
    bool c2 = d < 0.5f;
    bool c3 = d < 0.75f;
    float m0 = c1 ? 1.0f : 0.0f;
    float m1 = (c2 && !c1) ? 1.0f : 0.0f;
    float m2 = (c3 && !c2) ? 1.0f : 0.0f;
    float m3 = c3 ? 0.0f : 1.0f;
    acc[0] = fmaf(v, m0, acc[0]);
    acc[1] = fmaf(v, m1, acc[1]);
    acc[2] = fmaf(v, m2, acc[2]);
    acc[3] = fmaf(v, m3, acc[3]);
    cnt[0] += m0;
    cnt[1] += m1;
    cnt[2] += m2;
    cnt[3] += m3;
}

__device__ __forceinline__ void accum2v(const f32x4 xv, const f32x4 yv,
                                        const f32x2 dv,
                                        float (&acc)[NBINS], float (&cnt)[NBINS]) {
    accum_point(xv.x, xv.y, yv.x, yv.y, dv.x, acc, cnt);
    accum_point(xv.z, xv.w, yv.z, yv.w, dv.y, acc, cnt);
}

// nt loads (R3: +44%) + ISA-enforced depth-4 ring (R2/R5 structure; proven
// perf-equal to source pipeline — kept because it pins the schedule for clean
// A/B). R6 single variable: __launch_bounds__(256,8) -> 32 waves/CU, testing
// the per-wave return-serialization rival theory (all prior rounds ran
// 16 waves/CU; OccupancyPercent stuck ~50% despite VGPR=32/LDS=512B).
#define GLOAD4NT(dst, base, off) \
    asm volatile("global_load_dwordx4 %0, %1, %2 nt" : "=v"(dst) : "v"(off), "s"(base))
#define GLOAD2NT(dst, base, off) \
    asm volatile("global_load_dwordx2 %0, %1, %2 nt" : "=v"(dst) : "v"(off), "s"(base))
// Counted wait + rule-#18 fence (sched_barrier stops hipcc hoisting dependent
// VALU above the wait; "memory" alone does not order register-only ops).
#define VWAIT(n)                                              \
    do {                                                      \
        asm volatile("s_waitcnt vmcnt(" #n ")" ::: "memory"); \
        __builtin_amdgcn_sched_barrier(0);                    \
    } while (0)

__device__ __forceinline__ f32x4 ntload4(const f32x4* p) {
    return __builtin_nontemporal_load(p);
}
__device__ __forceinline__ f32x2 ntload2(const f32x2* p) {
    return __builtin_nontemporal_load(p);
}

__global__ __launch_bounds__(BLOCK, 8) void radial_loss_main(
    const float* __restrict__ x, const float* __restrict__ y,
    const float* __restrict__ dist, WS* __restrict__ ws, int n) {
    float acc[NBINS] = {0.f, 0.f, 0.f, 0.f};
    float cnt[NBINS] = {0.f, 0.f, 0.f, 0.f};

    const int n2 = n >> 1;  // float4(x,y) / float2(dist) index space: 2 points each
    const int stride = NBLOCKS * BLOCK;  // 524288; n2 = 16*stride at N=16.7M
    const int nfull = n2 / stride;       // uniform full steps for ALL threads
    int i = blockIdx.x * BLOCK + threadIdx.x;

    if (nfull >= 8 && (nfull & 3) == 0) {
        // ---- asm-pipelined nt path (taken for the bench shape: nfull == 16) ----
        f32x4 x0, y0, x1, y1, x2, y2, x3, y3;
        f32x2 d0, d1, d2, d3;
#define ISSUE(j, idx)                                       \
    do {                                                    \
        unsigned o16 = (unsigned)(idx) * 16u;               \
        unsigned o8 = (unsigned)(idx) * 8u;                 \
        GLOAD4NT(x##j, x, o16);                             \
        GLOAD4NT(y##j, y, o16);                             \
        GLOAD2NT(d##j, dist, o8);                           \
    } while (0)
        ISSUE(0, i);
        ISSUE(1, i + stride);
        ISSUE(2, i + 2 * stride);
        ISSUE(3, i + 3 * stride);
        int k = 0;
        for (; k + 8 <= nfull; k += 4) {
            VWAIT(9); accum2v(x0, y0, d0, acc, cnt); ISSUE(0, i + 4 * stride);
            VWAIT(9); accum2v(x1, y1, d1, acc, cnt); ISSUE(1, i + 5 * stride);
            VWAIT(9); accum2v(x2, y2, d2, acc, cnt); ISSUE(2, i + 6 * stride);
            VWAIT(9); accum2v(x3, y3, d3, acc, cnt); ISSUE(3, i + 7 * stride);
            i += 4 * stride;
        }
        // drain: exactly 4 stages (12 loads) outstanding here
        VWAIT(9); accum2v(x0, y0, d0, acc, cnt);
        VWAIT(6); accum2v(x1, y1, d1, acc, cnt);
        VWAIT(3); accum2v(x2, y2, d2, acc, cnt);
        VWAIT(0); accum2v(x3, y3, d3, acc, cnt);
        i += 4 * stride;
#undef ISSUE
    } else {
        // ---- generic fallback (not taken at N=16.7M) ----
        const f32x4* x4 = (const f32x4*)x;
        const f32x4* y4 = (const f32x4*)y;
        const f32x2* dd = (const f32x2*)dist;
        f32x4 xa, ya, xb, yb;
        f32x2 da, db;
        if (nfull >= 1) { xa = ntload4(x4 + i); ya = ntload4(y4 + i); da = ntload2(dd + i); }
        if (nfull >= 2) {
            xb = ntload4(x4 + i + stride);
            yb = ntload4(y4 + i + stride);
            db = ntload2(dd + i + stride);
        }
        for (int k = 0; k + 2 < nfull; ++k) {
            f32x4 xc = ntload4(x4 + i + 2 * stride);
            f32x4 yc = ntload4(y4 + i + 2 * stride);
            f32x2 dc = ntload2(dd + i + 2 * stride);
            accum2v(xa, ya, da, acc, cnt);
            xa = xb; ya = yb; da = db;
            xb = xc; yb = yc; db = dc;
            i += stride;
        }
        if (nfull >= 2) {
            accum2v(xa, ya, da, acc, cnt);
            xa = xb; ya = yb; da = db;
            i += stride;
        }
        if (nfull >= 1) {
            accum2v(xa, ya, da, acc, cnt);
            i += stride;
        }
    }

    // remainder region [nfull*stride, n2): each thread owns at most one index
    if (i < n2) {
        const f32x4* x4 = (const f32x4*)x;
        const f32x4* y4 = (const f32x4*)y;
        const f32x2* dd = (const f32x2*)dist;
        accum2v(ntload4(x4 + i), ntload4(y4 + i), ntload2(dd + i), acc, cnt);
    }
    // odd-n tail (n even in practice)
    if (blockIdx.x == 0) {
        for (int p = (n2 << 1) + threadIdx.x; p < n; p += BLOCK) {
            accum_point(x[2 * p], x[2 * p + 1], y[2 * p], y[2 * p + 1], dist[p],
                        acc, cnt);
        }
    }

    // wave-64 shuffle reduction (8 values)
#pragma unroll
    for (int off = 32; off > 0; off >>= 1) {
#pragma unroll
        for (int b = 0; b < NBINS; ++b) {
            acc[b] += __shfl_down(acc[b], off);
            cnt[b] += __shfl_down(cnt[b], off);
        }
    }

    __shared__ float sm_v[WAVES_PER_BLOCK][NBINS];
    __shared__ float sm_c[WAVES_PER_BLOCK][NBINS];
    const int wave = threadIdx.x >> 6;
    const int lane = threadIdx.x & 63;
    if (lane == 0) {
#pragma unroll
        for (int b = 0; b < NBINS; ++b) {
            sm_v[wave][b] = acc[b];
            sm_c[wave][b] = cnt[b];
        }
    }
    __syncthreads();
    if (threadIdx.x < NBINS) {
        const int b = threadIdx.x;
        float tv = 0.f, tc = 0.f;
#pragma unroll
        for (int w = 0; w < WAVES_PER_BLOCK; ++w) {
            tv += sm_v[w][b];
            tc += sm_c[w][b];
        }
        atomicAdd(&ws->sum_v[b], tv);
        atomicAdd(&ws->cnt[b], tc);
    }
}

__global__ void radial_loss_final(const WS* __restrict__ ws, float* __restrict__ out) {
    if (threadIdx.x == 0 && blockIdx.x == 0) {
        float loss = 0.f;
#pragma unroll
        for (int b = 0; b < NBINS; ++b) {
            float c = ws->cnt[b];
            if (c > 0.f) loss += ws->sum_v[b] / c;
        }
        out[0] = loss;
    }
}

extern "C" void kernel_launch(void* const* d_in, const int* in_sizes, int n_in,
                              void* d_out, int out_size, void* d_ws, size_t ws_size,
                              hipStream_t stream) {
    const float* x = (const float*)d_in[0];
    const float* y = (const float*)d_in[1];
    const float* dist = (const float*)d_in[2];
    float* out = (float*)d_out;
    WS* ws = (WS*)d_ws;
    const int n = in_sizes[2];  // dist element count = N

    hipMemsetAsync(ws, 0, sizeof(WS), stream);
    radial_loss_main<<<NBLOCKS, BLOCK, 0, stream>>>(x, y, dist, ws, n);
    radial_loss_final<<<1, 64, 0, stream>>>(ws, out);
}